// Round 5
// baseline (783.966 us; speedup 1.0000x reference)
//
#include <hip/hip_runtime.h>
#include <math.h>

typedef __bf16 bf16x8 __attribute__((ext_vector_type(8)));
typedef __bf16 bf16x4 __attribute__((ext_vector_type(4)));
typedef float f32x4 __attribute__((ext_vector_type(4)));

// 8 consecutive fp32 -> bf16x8 via native RNE casts (v_cvt_pk_bf16_f32)
__device__ __forceinline__ bf16x8 cvt8(const float* p) {
    f32x4 lo = *reinterpret_cast<const f32x4*>(p);
    f32x4 hi = *reinterpret_cast<const f32x4*>(p + 4);
    bf16x8 r;
#pragma unroll
    for (int i = 0; i < 4; ++i) { r[i] = (__bf16)lo[i]; r[i + 4] = (__bf16)hi[i]; }
    return r;
}

__device__ __forceinline__ float sigm(float v) {
    return 1.0f / (1.0f + __expf(-v));
}

// ---------------------------------------------------------------------------
// Full-K GEMM, no k-split, direct store with fused bias:
//   out[m,n] = bias[n] + sum_k A[m,k]*W[n,k]
// A: [64,K] bf16 row-major. W: [N,K] fp32 row-major. out: [64,N] fp32.
// Block = 4 waves; wave w owns n-tile (bx*4+w); 4 m-tiles (all 64 rows)/wave.
// grid = (N/64, 1, layers). MFMA 16x16x32 bf16; C/D: col=lane&15, row=quad*4+r.
// ---------------------------------------------------------------------------
__global__ __launch_bounds__(256) void gemm_ns(
    const __bf16* __restrict__ A, long long Asb,
    const float* __restrict__ W, long long Wsb,
    const float* __restrict__ bias, long long bsb,
    float* __restrict__ out, long long osb,
    int K, int N)
{
    const int l = threadIdx.x & 63;
    const int wave = threadIdx.x >> 6;
    const int lane16 = l & 15;
    const int quad = l >> 4;
    const int layer = blockIdx.z;
    const int n = (blockIdx.x * 4 + wave) * 16 + lane16;

    A += (long long)layer * Asb + quad * 8;
    const float* wp = W + (long long)layer * Wsb + (long long)n * K + quad * 8;
    const __bf16* ap0 = A + (long long)(lane16 +  0) * K;
    const __bf16* ap1 = A + (long long)(lane16 + 16) * K;
    const __bf16* ap2 = A + (long long)(lane16 + 32) * K;
    const __bf16* ap3 = A + (long long)(lane16 + 48) * K;

    f32x4 acc0 = {0.f, 0.f, 0.f, 0.f};
    f32x4 acc1 = acc0, acc2 = acc0, acc3 = acc0;

#pragma unroll 4
    for (int k = 0; k < K; k += 32) {
        bf16x8 b  = cvt8(wp + k);
        bf16x8 a0 = *reinterpret_cast<const bf16x8*>(ap0 + k);
        bf16x8 a1 = *reinterpret_cast<const bf16x8*>(ap1 + k);
        bf16x8 a2 = *reinterpret_cast<const bf16x8*>(ap2 + k);
        bf16x8 a3 = *reinterpret_cast<const bf16x8*>(ap3 + k);
        acc0 = __builtin_amdgcn_mfma_f32_16x16x32_bf16(a0, b, acc0, 0, 0, 0);
        acc1 = __builtin_amdgcn_mfma_f32_16x16x32_bf16(a1, b, acc1, 0, 0, 0);
        acc2 = __builtin_amdgcn_mfma_f32_16x16x32_bf16(a2, b, acc2, 0, 0, 0);
        acc3 = __builtin_amdgcn_mfma_f32_16x16x32_bf16(a3, b, acc3, 0, 0, 0);
    }

    const float bv = bias[(long long)layer * bsb + n];
    f32x4 accs[4] = {acc0, acc1, acc2, acc3};
    float* ob = out + (long long)layer * osb + n;
#pragma unroll
    for (int mt = 0; mt < 4; ++mt)
#pragma unroll
        for (int r = 0; r < 4; ++r) {
            const int m = mt * 16 + quad * 4 + r;
            ob[(long long)m * N] = accs[mt][r] + bv;
        }
}

// ---------------------------------------------------------------------------
// Small GEMM (N=1024), no k-split, fused epilogue.
// Block = n-tile (grid 64); wave = m-tile (16 rows). One acc f32x4 per thread.
// EPI 0: obf[m,c] = bf16(relu(acc+bias[c]))
// EPI 1: obf[m,c] = bf16(relu(acc+bias[c]) + att[m,c])
// EPI 2: of32[m,c] = acc + bias[c]           (pre-relu, consumers apply relu)
// ---------------------------------------------------------------------------
template <int EPI>
__global__ __launch_bounds__(256) void gemm_small(
    const __bf16* __restrict__ A, const float* __restrict__ W,
    const float* __restrict__ bias, const float* __restrict__ att,
    __bf16* __restrict__ obf, float* __restrict__ of32, int K)
{
    const int l = threadIdx.x & 63;
    const int wave = threadIdx.x >> 6;
    const int lane16 = l & 15;
    const int quad = l >> 4;
    const int c = blockIdx.x * 16 + lane16;

    const float* wp = W + (long long)c * K + quad * 8;
    const __bf16* ap = A + (long long)(wave * 16 + lane16) * K + quad * 8;

    f32x4 acc = {0.f, 0.f, 0.f, 0.f};
#pragma unroll 8
    for (int k = 0; k < K; k += 32) {
        bf16x8 b = cvt8(wp + k);
        bf16x8 a = *reinterpret_cast<const bf16x8*>(ap + k);
        acc = __builtin_amdgcn_mfma_f32_16x16x32_bf16(a, b, acc, 0, 0, 0);
    }

    const float bv = bias[c];
#pragma unroll
    for (int r = 0; r < 4; ++r) {
        const int m = wave * 16 + quad * 4 + r;
        float v = acc[r] + bv;
        if (EPI <= 1) {
            v = fmaxf(v, 0.0f);
            if (EPI == 1) v += att[m * 1024 + c];
            obf[m * 1024 + c] = (__bf16)v;
        } else {
            of32[m * 1024 + c] = v;
        }
    }
}

// ---------------------------------------------------------------------------
// Fused GRU layer: gi = xin @ Wih.T (+bih) for all 3 gates of a 16-col slice,
// then the full GRU pointwise in-register. No gi buffer, no atomics.
// Block = col-slice (grid 64); wave = m-tile. gh buffer already contains bhh.
// ---------------------------------------------------------------------------
__global__ __launch_bounds__(256) void gru_layer(
    const __bf16* __restrict__ xin, const float* __restrict__ Wih,
    const float* __restrict__ ghl, const float* __restrict__ hid_l,
    const float* __restrict__ attnb, const float* __restrict__ bih,
    const float* __restrict__ oprev,
    float* __restrict__ o_out, float* __restrict__ o_h1,
    __bf16* __restrict__ xnext)
{
    const int l = threadIdx.x & 63;
    const int wave = threadIdx.x >> 6;
    const int lane16 = l & 15;
    const int quad = l >> 4;
    const int c = blockIdx.x * 16 + lane16;

    const __bf16* ap = xin + (long long)(wave * 16 + lane16) * 1024 + quad * 8;
    const float* wp0 = Wih + (long long)(c       ) * 1024 + quad * 8;
    const float* wp1 = Wih + (long long)(c + 1024) * 1024 + quad * 8;
    const float* wp2 = Wih + (long long)(c + 2048) * 1024 + quad * 8;

    f32x4 acc0 = {0.f, 0.f, 0.f, 0.f};
    f32x4 acc1 = acc0, acc2 = acc0;

#pragma unroll 4
    for (int k = 0; k < 1024; k += 32) {
        bf16x8 a  = *reinterpret_cast<const bf16x8*>(ap + k);
        bf16x8 b0 = cvt8(wp0 + k);
        bf16x8 b1 = cvt8(wp1 + k);
        bf16x8 b2 = cvt8(wp2 + k);
        acc0 = __builtin_amdgcn_mfma_f32_16x16x32_bf16(a, b0, acc0, 0, 0, 0);
        acc1 = __builtin_amdgcn_mfma_f32_16x16x32_bf16(a, b1, acc1, 0, 0, 0);
        acc2 = __builtin_amdgcn_mfma_f32_16x16x32_bf16(a, b2, acc2, 0, 0, 0);
    }

    const float b_r = bih[c], b_z = bih[c + 1024], b_n = bih[c + 2048];
#pragma unroll
    for (int r = 0; r < 4; ++r) {
        const int m = wave * 16 + quad * 4 + r;
        const float i_r = acc0[r] + b_r;
        const float i_z = acc1[r] + b_z;
        const float i_n = acc2[r] + b_n;
        const float h_r = ghl[m * 3072 + c];
        const float h_z = ghl[m * 3072 + c + 1024];
        const float h_n = ghl[m * 3072 + c + 2048];
        const float rr = sigm(i_r + h_r);
        const float z  = sigm(i_z + h_z);
        const float nv = tanhf(i_n + rr * h_n);
        const float hcur = hid_l[m * 1024 + c] + fmaxf(attnb[m * 1024 + c], 0.0f);
        const float x = (1.0f - z) * nv + z * hcur;
        o_out[m * 1024 + c] = x;
        if (o_h1) o_h1[m * 1024 + c] = x;
        float xi = x;
        if (oprev) xi += oprev[m * 1024 + c];
        xnext[m * 1024 + c] = (__bf16)xi;
    }
}

// fp32 -> bf16 convert, vec4/thread (feature pre-convert)
__global__ __launch_bounds__(256) void conv_bf(
    const float* __restrict__ in, __bf16* __restrict__ out, int total4)
{
    const int gid = blockIdx.x * 256 + threadIdx.x;
    if (gid >= total4) return;
    f32x4 v = reinterpret_cast<const f32x4*>(in)[gid];
    bf16x4 o;
#pragma unroll
    for (int i = 0; i < 4; ++i) o[i] = (__bf16)v[i];
    reinterpret_cast<bf16x4*>(out)[gid] = o;
}

// xe = bf16(relu(emb[x]))  -> [64,1024] bf16, vec4/thread
__global__ __launch_bounds__(256) void gather_relu(
    const float* __restrict__ emb, const int* __restrict__ xidx,
    __bf16* __restrict__ xe)
{
    const int gid = blockIdx.x * 256 + threadIdx.x;  // 16384 total
    const int m = gid >> 8, e = (gid & 255) << 2;
    f32x4 v = *reinterpret_cast<const f32x4*>(emb + (long long)xidx[m] * 1024 + e);
    bf16x4 o;
#pragma unroll
    for (int i = 0; i < 4; ++i) o[i] = (__bf16)fmaxf(v[i], 0.0f);
    *reinterpret_cast<bf16x4*>(xe + ((long long)m << 10) + e) = o;
}

// hbf[i] = bf16(hiddens[i] + relu(attnb))  -> [8,64,1024] bf16, vec4/thread
__global__ __launch_bounds__(256) void hsum(
    const float* __restrict__ hiddens, const float* __restrict__ attn,
    __bf16* __restrict__ hbf)
{
    const int gid = blockIdx.x * 256 + threadIdx.x;  // 131072 vec4 total
    f32x4 hv = reinterpret_cast<const f32x4*>(hiddens)[gid];
    f32x4 av = reinterpret_cast<const f32x4*>(attn)[gid & 16383];
    bf16x4 o;
#pragma unroll
    for (int i = 0; i < 4; ++i) o[i] = (__bf16)(hv[i] + fmaxf(av[i], 0.0f));
    reinterpret_cast<bf16x4*>(hbf)[gid] = o;
}

// fused log_softmax in place over [64,32000]: max, sumexp, subtract lse
__global__ __launch_bounds__(256) void softmax_k(float* __restrict__ logits)
{
    const int m = blockIdx.x;
    f32x4* row = reinterpret_cast<f32x4*>(logits + (long long)m * 32000);
    __shared__ float red[256];
    const int tid = threadIdx.x;
    float mx = -1e30f;
    for (int i = tid; i < 8000; i += 256) {
        f32x4 v = row[i];
        mx = fmaxf(mx, fmaxf(fmaxf(v[0], v[1]), fmaxf(v[2], v[3])));
    }
    red[tid] = mx;
    __syncthreads();
    for (int off = 128; off > 0; off >>= 1) {
        if (tid < off) red[tid] = fmaxf(red[tid], red[tid + off]);
        __syncthreads();
    }
    mx = red[0];
    __syncthreads();
    float s = 0.0f;
    for (int i = tid; i < 8000; i += 256) {
        f32x4 v = row[i];
        s += __expf(v[0] - mx) + __expf(v[1] - mx) + __expf(v[2] - mx) + __expf(v[3] - mx);
    }
    red[tid] = s;
    __syncthreads();
    for (int off = 128; off > 0; off >>= 1) {
        if (tid < off) red[tid] += red[tid + off];
        __syncthreads();
    }
    const float lse = mx + logf(red[0]);
    __syncthreads();
    for (int i = tid; i < 8000; i += 256) {
        f32x4 v = row[i];
        v[0] -= lse; v[1] -= lse; v[2] -= lse; v[3] -= lse;
        row[i] = v;
    }
}

extern "C" void kernel_launch(void* const* d_in, const int* in_sizes, int n_in,
                              void* d_out, int out_size, void* d_ws, size_t ws_size,
                              hipStream_t stream)
{
    const float* feature   = (const float*)d_in[0];   // [64,2048]
    const int*   x         = (const int*)d_in[1];     // [64]
    const float* attention = (const float*)d_in[2];   // [64,1024]
    const float* hiddens   = (const float*)d_in[3];   // [8,64,1024]
    const float* emb       = (const float*)d_in[4];   // [32000,1024]
    const float* map_W     = (const float*)d_in[5];   // [1024,2048]
    const float* map_b     = (const float*)d_in[6];
    const float* ai_W      = (const float*)d_in[7];
    const float* ai_b      = (const float*)d_in[8];
    const float* ah_W      = (const float*)d_in[9];
    const float* ah_b      = (const float*)d_in[10];
    const float* ao_W      = (const float*)d_in[11];
    const float* ao_b      = (const float*)d_in[12];
    const float* gru_Wih   = (const float*)d_in[13];  // [8,3072,1024]
    const float* gru_Whh   = (const float*)d_in[14];  // [8,3072,1024]
    const float* gru_bih   = (const float*)d_in[15];  // [8,3072]
    const float* gru_bhh   = (const float*)d_in[16];  // [8,3072]
    const float* out_W     = (const float*)d_in[17];  // [32000,1024]
    const float* out_b     = (const float*)d_in[18];  // [32000]

    float* out      = (float*)d_out;
    float* out_logp = out;                    // [64,32000]
    float* out_h1   = out + 2048000;          // [64,1024]
    float* out_nh   = out + 2048000 + 65536;  // [8,64,1024]

    // Workspace layout (float units). bf16 [64,1024] = 32768 floats;
    // featb [64,2048] = 65536 floats; hbf [8,64,1024] = 262144 floats.
    float* w = (float*)d_ws;
    float*  attnb = w + 0;                    // [0, 65536)
    float*  gh    = w + 65536;                // [65536, 1638400)
    __bf16* featb = (__bf16*)(w + 1638400);   // [1638400, 1703936)
    __bf16* a1A   = (__bf16*)(w + 1703936);   // [1703936, 1736704)
    __bf16* a2A   = (__bf16*)(w + 1736704);   // [1736704, 1769472)
    __bf16* a3A   = (__bf16*)(w + 1769472);   // [1769472, 1802240)
    __bf16* xinA  = (__bf16*)(w + 1802240);   // [1802240, 1835008)
    __bf16* xinB  = (__bf16*)(w + 1835008);   // [1835008, 1867776)
    __bf16* hbf   = (__bf16*)(w + 1867776);   // [1867776, 2129920)
    __bf16* xbuf[2] = {xinA, xinB};

    // xe = bf16(relu(emb[x]))
    gather_relu<<<64, 256, 0, stream>>>(emb, x, xinA);
    // featb = bf16(feature)
    conv_bf<<<128, 256, 0, stream>>>(feature, featb, 32768);

    // attn chain, fully fused epilogues (N=1024 each):
    // a1A = bf16(relu(featb@map_W.T + map_b) + attention)
    gemm_small<1><<<64, 256, 0, stream>>>(featb, map_W, map_b, attention,
                                          a1A, nullptr, 2048);
    // a2A = bf16(relu(a1A@ai_W.T + ai_b))
    gemm_small<0><<<64, 256, 0, stream>>>(a1A, ai_W, ai_b, nullptr,
                                          a2A, nullptr, 1024);
    // a3A = bf16(relu(a2A@ah_W.T + ah_b))
    gemm_small<0><<<64, 256, 0, stream>>>(a2A, ah_W, ah_b, nullptr,
                                          a3A, nullptr, 1024);
    // attnb = a3A@ao_W.T + ao_b   (fp32, pre-relu)
    gemm_small<2><<<64, 256, 0, stream>>>(a3A, ao_W, ao_b, nullptr,
                                          nullptr, attnb, 1024);

    // hbf[i] = bf16(hiddens[i] + relu(attnb))
    hsum<<<512, 256, 0, stream>>>(hiddens, attnb, hbf);

    // gh[i] = hbf[i] @ Whh[i].T + bhh[i]   (batched, direct store)
    gemm_ns<<<dim3(48, 1, 8), 256, 0, stream>>>(hbf, 65536, gru_Whh, 3145728,
                                                gru_bhh, 3072, gh, 196608,
                                                1024, 3072);

    // sequential fused GRU chain (GEMM + pointwise per layer, ping-pong xin)
    for (int c = 0; c < 8; ++c) {
        gru_layer<<<64, 256, 0, stream>>>(
            xbuf[c & 1], gru_Wih + (long long)c * 3145728,
            gh + (long long)c * 196608,
            hiddens + (long long)c * 65536, attnb,
            gru_bih + (long long)c * 3072,
            (c >= 2 && c < 7) ? out_nh + (long long)(c - 1) * 65536 : nullptr,
            out_nh + (long long)c * 65536,
            (c == 0) ? out_h1 : nullptr,
            xbuf[(c + 1) & 1]);   // c==7 writes xbuf[0] = bf16(x8)
    }

    // logits = x8 @ out_W.T + out_b   (direct store, no k-split)
    gemm_ns<<<dim3(500, 1, 1), 256, 0, stream>>>(xbuf[0], 0, out_W, 0,
                                                 out_b, 0, out_logp, 0,
                                                 1024, 32000);

    // fused log_softmax in place
    softmax_k<<<64, 256, 0, stream>>>(out_logp);
}

// Round 6
// 646.522 us; speedup vs baseline: 1.2126x; 1.2126x over previous
//
#include <hip/hip_runtime.h>
#include <math.h>

typedef __bf16 bf16x8 __attribute__((ext_vector_type(8)));
typedef __bf16 bf16x4 __attribute__((ext_vector_type(4)));
typedef float f32x4 __attribute__((ext_vector_type(4)));

// 8 consecutive fp32 -> bf16x8 via native RNE casts (v_cvt_pk_bf16_f32)
__device__ __forceinline__ bf16x8 cvt8(const float* p) {
    f32x4 lo = *reinterpret_cast<const f32x4*>(p);
    f32x4 hi = *reinterpret_cast<const f32x4*>(p + 4);
    bf16x8 r;
#pragma unroll
    for (int i = 0; i < 4; ++i) { r[i] = (__bf16)lo[i]; r[i + 4] = (__bf16)hi[i]; }
    return r;
}

__device__ __forceinline__ float sigm(float v) {
    return 1.0f / (1.0f + __expf(-v));
}

// ---------------------------------------------------------------------------
// Full-K GEMM, no k-split, direct store with fused bias:
//   out[m,n] = bias[n] + sum_k A[m,k]*W[n,k]
// A: [64,K] bf16 row-major. W: [N,K] fp32 row-major. out: [64,N] fp32.
// Block = 4 waves; wave w owns n-tile (bx*4+w); 4 m-tiles (all 64 rows)/wave.
// grid = (N/64, 1, layers). MFMA 16x16x32 bf16; C/D: col=lane&15, row=quad*4+r.
// ---------------------------------------------------------------------------
__global__ __launch_bounds__(256) void gemm_ns(
    const __bf16* __restrict__ A, long long Asb,
    const float* __restrict__ W, long long Wsb,
    const float* __restrict__ bias, long long bsb,
    float* __restrict__ out, long long osb,
    int K, int N)
{
    const int l = threadIdx.x & 63;
    const int wave = threadIdx.x >> 6;
    const int lane16 = l & 15;
    const int quad = l >> 4;
    const int layer = blockIdx.z;
    const int n = (blockIdx.x * 4 + wave) * 16 + lane16;

    A += (long long)layer * Asb + quad * 8;
    const float* wp = W + (long long)layer * Wsb + (long long)n * K + quad * 8;
    const __bf16* ap0 = A + (long long)(lane16 +  0) * K;
    const __bf16* ap1 = A + (long long)(lane16 + 16) * K;
    const __bf16* ap2 = A + (long long)(lane16 + 32) * K;
    const __bf16* ap3 = A + (long long)(lane16 + 48) * K;

    f32x4 acc0 = {0.f, 0.f, 0.f, 0.f};
    f32x4 acc1 = acc0, acc2 = acc0, acc3 = acc0;

#pragma unroll 4
    for (int k = 0; k < K; k += 32) {
        bf16x8 b  = cvt8(wp + k);
        bf16x8 a0 = *reinterpret_cast<const bf16x8*>(ap0 + k);
        bf16x8 a1 = *reinterpret_cast<const bf16x8*>(ap1 + k);
        bf16x8 a2 = *reinterpret_cast<const bf16x8*>(ap2 + k);
        bf16x8 a3 = *reinterpret_cast<const bf16x8*>(ap3 + k);
        acc0 = __builtin_amdgcn_mfma_f32_16x16x32_bf16(a0, b, acc0, 0, 0, 0);
        acc1 = __builtin_amdgcn_mfma_f32_16x16x32_bf16(a1, b, acc1, 0, 0, 0);
        acc2 = __builtin_amdgcn_mfma_f32_16x16x32_bf16(a2, b, acc2, 0, 0, 0);
        acc3 = __builtin_amdgcn_mfma_f32_16x16x32_bf16(a3, b, acc3, 0, 0, 0);
    }

    const float bv = bias[(long long)layer * bsb + n];
    f32x4 accs[4] = {acc0, acc1, acc2, acc3};
    float* ob = out + (long long)layer * osb + n;
#pragma unroll
    for (int mt = 0; mt < 4; ++mt)
#pragma unroll
        for (int r = 0; r < 4; ++r) {
            const int m = mt * 16 + quad * 4 + r;
            ob[(long long)m * N] = accs[mt][r] + bv;
        }
}

// ---------------------------------------------------------------------------
// K-split partial GEMM (no bias): part[ks][m][n] = sum_{k in chunk ks} A*W
// grid = (N/64, KS); block = 4 waves, wave owns n-tile, 4 m-tiles/wave.
// Plain stores; partial buffer needs no init (fully overwritten).
// ---------------------------------------------------------------------------
__global__ __launch_bounds__(256) void gemm_part(
    const __bf16* __restrict__ A, const float* __restrict__ W,
    float* __restrict__ part, int K, int KC, int N)
{
    const int l = threadIdx.x & 63;
    const int wave = threadIdx.x >> 6;
    const int lane16 = l & 15;
    const int quad = l >> 4;
    const int n = (blockIdx.x * 4 + wave) * 16 + lane16;
    const int k0 = blockIdx.y * KC;

    A += k0 + quad * 8;
    const float* wp = W + (long long)n * K + k0 + quad * 8;
    const __bf16* ap0 = A + (long long)(lane16 +  0) * K;
    const __bf16* ap1 = A + (long long)(lane16 + 16) * K;
    const __bf16* ap2 = A + (long long)(lane16 + 32) * K;
    const __bf16* ap3 = A + (long long)(lane16 + 48) * K;

    f32x4 acc0 = {0.f, 0.f, 0.f, 0.f};
    f32x4 acc1 = acc0, acc2 = acc0, acc3 = acc0;

#pragma unroll 4
    for (int k = 0; k < KC; k += 32) {
        bf16x8 b  = cvt8(wp + k);
        bf16x8 a0 = *reinterpret_cast<const bf16x8*>(ap0 + k);
        bf16x8 a1 = *reinterpret_cast<const bf16x8*>(ap1 + k);
        bf16x8 a2 = *reinterpret_cast<const bf16x8*>(ap2 + k);
        bf16x8 a3 = *reinterpret_cast<const bf16x8*>(ap3 + k);
        acc0 = __builtin_amdgcn_mfma_f32_16x16x32_bf16(a0, b, acc0, 0, 0, 0);
        acc1 = __builtin_amdgcn_mfma_f32_16x16x32_bf16(a1, b, acc1, 0, 0, 0);
        acc2 = __builtin_amdgcn_mfma_f32_16x16x32_bf16(a2, b, acc2, 0, 0, 0);
        acc3 = __builtin_amdgcn_mfma_f32_16x16x32_bf16(a3, b, acc3, 0, 0, 0);
    }

    f32x4 accs[4] = {acc0, acc1, acc2, acc3};
    float* ob = part + (long long)blockIdx.y * 64 * N + n;
#pragma unroll
    for (int mt = 0; mt < 4; ++mt)
#pragma unroll
        for (int r = 0; r < 4; ++r) {
            const int m = mt * 16 + quad * 4 + r;
            ob[(long long)m * N] = accs[mt][r];
        }
}

// ---------------------------------------------------------------------------
// GRU pointwise + 8-way partial reduction (N=3072, KS=8 fixed).
// Thread = (m,c). gi gates = bih + sum_ks part[ks][m][gate*1024+c].
// ---------------------------------------------------------------------------
__global__ __launch_bounds__(256) void gru_pw_red(
    const float* __restrict__ part, const float* __restrict__ ghl,
    const float* __restrict__ hid_l, const float* __restrict__ attnb,
    const float* __restrict__ bih, const float* __restrict__ oprev,
    float* __restrict__ o_out, float* __restrict__ o_h1,
    __bf16* __restrict__ xnext)
{
    const int gid = blockIdx.x * 256 + threadIdx.x;  // 65536 total
    const int m = gid >> 10, c = gid & 1023;
    float i_r = bih[c], i_z = bih[c + 1024], i_n = bih[c + 2048];
#pragma unroll
    for (int ks = 0; ks < 8; ++ks) {
        const float* p = part + ks * 196608 + m * 3072;
        i_r += p[c]; i_z += p[c + 1024]; i_n += p[c + 2048];
    }
    const float h_r = ghl[m * 3072 + c];
    const float h_z = ghl[m * 3072 + c + 1024];
    const float h_n = ghl[m * 3072 + c + 2048];
    const float rr = sigm(i_r + h_r);
    const float z  = sigm(i_z + h_z);
    const float nv = tanhf(i_n + rr * h_n);
    const float hcur = hid_l[gid] + fmaxf(attnb[gid], 0.0f);
    const float x = (1.0f - z) * nv + z * hcur;
    o_out[gid] = x;
    if (o_h1) o_h1[gid] = x;
    float xi = x;
    if (oprev) xi += oprev[gid];
    xnext[gid] = (__bf16)xi;
}

// ---------------------------------------------------------------------------
// Small GEMM (N=1024), no k-split, fused epilogue.
// Block = n-tile (grid 64); wave = m-tile (16 rows). One acc f32x4 per thread.
// EPI 0: obf[m,c] = bf16(relu(acc+bias[c]))
// EPI 1: obf[m,c] = bf16(relu(acc+bias[c]) + att[m,c])
// EPI 2: of32[m,c] = acc + bias[c]           (pre-relu, consumers apply relu)
// ---------------------------------------------------------------------------
template <int EPI>
__global__ __launch_bounds__(256) void gemm_small(
    const __bf16* __restrict__ A, const float* __restrict__ W,
    const float* __restrict__ bias, const float* __restrict__ att,
    __bf16* __restrict__ obf, float* __restrict__ of32, int K)
{
    const int l = threadIdx.x & 63;
    const int wave = threadIdx.x >> 6;
    const int lane16 = l & 15;
    const int quad = l >> 4;
    const int c = blockIdx.x * 16 + lane16;

    const float* wp = W + (long long)c * K + quad * 8;
    const __bf16* ap = A + (long long)(wave * 16 + lane16) * K + quad * 8;

    f32x4 acc = {0.f, 0.f, 0.f, 0.f};
#pragma unroll 8
    for (int k = 0; k < K; k += 32) {
        bf16x8 b = cvt8(wp + k);
        bf16x8 a = *reinterpret_cast<const bf16x8*>(ap + k);
        acc = __builtin_amdgcn_mfma_f32_16x16x32_bf16(a, b, acc, 0, 0, 0);
    }

    const float bv = bias[c];
#pragma unroll
    for (int r = 0; r < 4; ++r) {
        const int m = wave * 16 + quad * 4 + r;
        float v = acc[r] + bv;
        if (EPI <= 1) {
            v = fmaxf(v, 0.0f);
            if (EPI == 1) v += att[m * 1024 + c];
            obf[m * 1024 + c] = (__bf16)v;
        } else {
            of32[m * 1024 + c] = v;
        }
    }
}

// fp32 -> bf16 convert, vec4/thread (feature pre-convert)
__global__ __launch_bounds__(256) void conv_bf(
    const float* __restrict__ in, __bf16* __restrict__ out, int total4)
{
    const int gid = blockIdx.x * 256 + threadIdx.x;
    if (gid >= total4) return;
    f32x4 v = reinterpret_cast<const f32x4*>(in)[gid];
    bf16x4 o;
#pragma unroll
    for (int i = 0; i < 4; ++i) o[i] = (__bf16)v[i];
    reinterpret_cast<bf16x4*>(out)[gid] = o;
}

// xe = bf16(relu(emb[x]))  -> [64,1024] bf16, vec4/thread
__global__ __launch_bounds__(256) void gather_relu(
    const float* __restrict__ emb, const int* __restrict__ xidx,
    __bf16* __restrict__ xe)
{
    const int gid = blockIdx.x * 256 + threadIdx.x;  // 16384 total
    const int m = gid >> 8, e = (gid & 255) << 2;
    f32x4 v = *reinterpret_cast<const f32x4*>(emb + (long long)xidx[m] * 1024 + e);
    bf16x4 o;
#pragma unroll
    for (int i = 0; i < 4; ++i) o[i] = (__bf16)fmaxf(v[i], 0.0f);
    *reinterpret_cast<bf16x4*>(xe + ((long long)m << 10) + e) = o;
}

// hbf[i] = bf16(hiddens[i] + relu(attnb))  -> [8,64,1024] bf16, vec4/thread
__global__ __launch_bounds__(256) void hsum(
    const float* __restrict__ hiddens, const float* __restrict__ attn,
    __bf16* __restrict__ hbf)
{
    const int gid = blockIdx.x * 256 + threadIdx.x;  // 131072 vec4 total
    f32x4 hv = reinterpret_cast<const f32x4*>(hiddens)[gid];
    f32x4 av = reinterpret_cast<const f32x4*>(attn)[gid & 16383];
    bf16x4 o;
#pragma unroll
    for (int i = 0; i < 4; ++i) o[i] = (__bf16)(hv[i] + fmaxf(av[i], 0.0f));
    reinterpret_cast<bf16x4*>(hbf)[gid] = o;
}

// fused log_softmax in place over [64,32000]: max, sumexp, subtract lse
__global__ __launch_bounds__(256) void softmax_k(float* __restrict__ logits)
{
    const int m = blockIdx.x;
    f32x4* row = reinterpret_cast<f32x4*>(logits + (long long)m * 32000);
    __shared__ float red[256];
    const int tid = threadIdx.x;
    float mx = -1e30f;
    for (int i = tid; i < 8000; i += 256) {
        f32x4 v = row[i];
        mx = fmaxf(mx, fmaxf(fmaxf(v[0], v[1]), fmaxf(v[2], v[3])));
    }
    red[tid] = mx;
    __syncthreads();
    for (int off = 128; off > 0; off >>= 1) {
        if (tid < off) red[tid] = fmaxf(red[tid], red[tid + off]);
        __syncthreads();
    }
    mx = red[0];
    __syncthreads();
    float s = 0.0f;
    for (int i = tid; i < 8000; i += 256) {
        f32x4 v = row[i];
        s += __expf(v[0] - mx) + __expf(v[1] - mx) + __expf(v[2] - mx) + __expf(v[3] - mx);
    }
    red[tid] = s;
    __syncthreads();
    for (int off = 128; off > 0; off >>= 1) {
        if (tid < off) red[tid] += red[tid + off];
        __syncthreads();
    }
    const float lse = mx + logf(red[0]);
    __syncthreads();
    for (int i = tid; i < 8000; i += 256) {
        f32x4 v = row[i];
        v[0] -= lse; v[1] -= lse; v[2] -= lse; v[3] -= lse;
        row[i] = v;
    }
}

extern "C" void kernel_launch(void* const* d_in, const int* in_sizes, int n_in,
                              void* d_out, int out_size, void* d_ws, size_t ws_size,
                              hipStream_t stream)
{
    const float* feature   = (const float*)d_in[0];   // [64,2048]
    const int*   x         = (const int*)d_in[1];     // [64]
    const float* attention = (const float*)d_in[2];   // [64,1024]
    const float* hiddens   = (const float*)d_in[3];   // [8,64,1024]
    const float* emb       = (const float*)d_in[4];   // [32000,1024]
    const float* map_W     = (const float*)d_in[5];   // [1024,2048]
    const float* map_b     = (const float*)d_in[6];
    const float* ai_W      = (const float*)d_in[7];
    const float* ai_b      = (const float*)d_in[8];
    const float* ah_W      = (const float*)d_in[9];
    const float* ah_b      = (const float*)d_in[10];
    const float* ao_W      = (const float*)d_in[11];
    const float* ao_b      = (const float*)d_in[12];
    const float* gru_Wih   = (const float*)d_in[13];  // [8,3072,1024]
    const float* gru_Whh   = (const float*)d_in[14];  // [8,3072,1024]
    const float* gru_bih   = (const float*)d_in[15];  // [8,3072]
    const float* gru_bhh   = (const float*)d_in[16];  // [8,3072]
    const float* out_W     = (const float*)d_in[17];  // [32000,1024]
    const float* out_b     = (const float*)d_in[18];  // [32000]

    float* out      = (float*)d_out;
    float* out_logp = out;                    // [64,32000]
    float* out_h1   = out + 2048000;          // [64,1024]
    float* out_nh   = out + 2048000 + 65536;  // [8,64,1024]

    // Workspace layout (float units). bf16 [64,1024] = 32768 floats;
    // featb [64,2048] = 65536 floats; hbf [8,64,1024] = 262144 floats;
    // part [8][64][3072] = 1572864 floats.
    float* w = (float*)d_ws;
    float*  attnb = w + 0;                    // [0, 65536)
    float*  gh    = w + 65536;                // [65536, 1638400)
    float*  part  = w + 1638400;              // [1638400, 3211264)
    __bf16* featb = (__bf16*)(w + 3211264);   // [3211264, 3276800)
    __bf16* a1A   = (__bf16*)(w + 3276800);   // [3276800, 3309568)
    __bf16* a2A   = (__bf16*)(w + 3309568);   // [3309568, 3342336)
    __bf16* a3A   = (__bf16*)(w + 3342336);   // [3342336, 3375104)
    __bf16* xinA  = (__bf16*)(w + 3375104);   // [3375104, 3407872)
    __bf16* xinB  = (__bf16*)(w + 3407872);   // [3407872, 3440640)
    __bf16* hbf   = (__bf16*)(w + 3440640);   // [3440640, 3702784)
    __bf16* xbuf[2] = {xinA, xinB};

    // xe = bf16(relu(emb[x]))
    gather_relu<<<64, 256, 0, stream>>>(emb, x, xinA);
    // featb = bf16(feature)
    conv_bf<<<128, 256, 0, stream>>>(feature, featb, 32768);

    // attn chain, fully fused epilogues (N=1024 each):
    // a1A = bf16(relu(featb@map_W.T + map_b) + attention)
    gemm_small<1><<<64, 256, 0, stream>>>(featb, map_W, map_b, attention,
                                          a1A, nullptr, 2048);
    // a2A = bf16(relu(a1A@ai_W.T + ai_b))
    gemm_small<0><<<64, 256, 0, stream>>>(a1A, ai_W, ai_b, nullptr,
                                          a2A, nullptr, 1024);
    // a3A = bf16(relu(a2A@ah_W.T + ah_b))
    gemm_small<0><<<64, 256, 0, stream>>>(a2A, ah_W, ah_b, nullptr,
                                          a3A, nullptr, 1024);
    // attnb = a3A@ao_W.T + ao_b   (fp32, pre-relu)
    gemm_small<2><<<64, 256, 0, stream>>>(a3A, ao_W, ao_b, nullptr,
                                          nullptr, attnb, 1024);

    // hbf[i] = bf16(hiddens[i] + relu(attnb))
    hsum<<<512, 256, 0, stream>>>(hiddens, attnb, hbf);

    // gh[i] = hbf[i] @ Whh[i].T + bhh[i]   (batched, direct store)
    gemm_ns<<<dim3(48, 1, 8), 256, 0, stream>>>(hbf, 65536, gru_Whh, 3145728,
                                                gru_bhh, 3072, gh, 196608,
                                                1024, 3072);

    // sequential GRU chain: k-split partial GEMM (384 blocks, full CU
    // coverage) + pointwise reduce per layer; ping-pong xin buffers.
    for (int c = 0; c < 8; ++c) {
        gemm_part<<<dim3(48, 8), 256, 0, stream>>>(
            xbuf[c & 1], gru_Wih + (long long)c * 3145728, part,
            1024, 128, 3072);
        gru_pw_red<<<256, 256, 0, stream>>>(
            part, gh + (long long)c * 196608,
            hiddens + (long long)c * 65536, attnb,
            gru_bih + (long long)c * 3072,
            (c >= 2 && c < 7) ? out_nh + (long long)(c - 1) * 65536 : nullptr,
            out_nh + (long long)c * 65536,
            (c == 0) ? out_h1 : nullptr,
            xbuf[(c + 1) & 1]);   // c==7 writes xbuf[0] = bf16(x8)
    }

    // logits = x8 @ out_W.T + out_b   (direct store, no k-split)
    gemm_ns<<<dim3(500, 1, 1), 256, 0, stream>>>(xbuf[0], 0, out_W, 0,
                                                 out_b, 0, out_logp, 0,
                                                 1024, 32000);

    // fused log_softmax in place
    softmax_k<<<64, 256, 0, stream>>>(out_logp);
}